// Round 2
// baseline (922.383 us; speedup 1.0000x reference)
//
#include <hip/hip_runtime.h>

typedef short short8 __attribute__((ext_vector_type(8)));
typedef float f32x4 __attribute__((ext_vector_type(4)));
typedef unsigned short u16;
typedef unsigned int u32;

#define Bq 4
#define Sq 4096
#define Hq 16
#define Dq 128
#define CHUNK 1024
#define QT 64
#define KT 64
#define HD (Hq*Dq) /* 2048: row stride in elements */
#define LOG2E 1.44269504088896f
#define SCALE 0.08838834764831845f /* 1/sqrt(128) */

__device__ __forceinline__ u16 f2bf(float f) {
    union { float f; u32 u; } v; v.f = f;
    u32 r = v.u + 0x7fffu + ((v.u >> 16) & 1u);
    return (u16)(r >> 16);
}

__global__ __launch_bounds__(256, 3) void attn_sink_kernel(
    const float* __restrict__ qg, const float* __restrict__ kg,
    const float* __restrict__ vg, const float* __restrict__ sg,
    float* __restrict__ og)
{
    // K tile: row-major [KT][128] bf16, 8-elem chunks XOR-swizzled by (row&7)
    __shared__ __align__(16) u16 Ksh[KT * Dq];          // 16 KB
    // V tile transposed: [d][kv] bf16, pitch KT, chunks swizzled by (d&7)
    __shared__ __align__(16) u16 Vsh[Dq * KT];          // 16 KB
    // per-wave P scratch [16][KT] bf16, chunks swizzled by (row&7)
    __shared__ __align__(16) u16 Psh[4][16 * KT];       // 8 KB

    const int tid  = threadIdx.x;
    const int lane = tid & 63;
    const int wave = tid >> 6;
    const int l16  = lane & 15;
    const int quad = lane >> 4;

    const int bid = blockIdx.x;
    const int qt  = bid & 15;          // q-tile within chunk
    const int nch = (bid >> 4) & 3;    // chunk index
    const int h   = (bid >> 6) & 15;   // head
    const int b   = bid >> 10;         // batch

    const int s0    = nch * CHUNK;
    const int qrow0 = qt * QT + wave * 16;   // within-chunk row base for this wave

    const size_t base = ((size_t)b * Sq + s0) * HD + (size_t)h * Dq;

    // ---- Q fragments (A-operand layout): lane holds Q[row=l16][k = ks*32+quad*8 .. +7]
    short8 qf[4];
    {
        const float* qrow = qg + base + (size_t)(qrow0 + l16) * HD + quad * 8;
        #pragma unroll
        for (int ks = 0; ks < 4; ++ks) {
            float4 x = *(const float4*)(qrow + ks * 32);
            float4 y = *(const float4*)(qrow + ks * 32 + 4);
            short8 pk;
            pk[0] = (short)f2bf(x.x); pk[1] = (short)f2bf(x.y);
            pk[2] = (short)f2bf(x.z); pk[3] = (short)f2bf(x.w);
            pk[4] = (short)f2bf(y.x); pk[5] = (short)f2bf(y.y);
            pk[6] = (short)f2bf(y.z); pk[7] = (short)f2bf(y.w);
            qf[ks] = pk;
        }
    }

    const float sinkv = sg[h];

    float m_r[4], l_r[4];
    f32x4 O[8];
    #pragma unroll
    for (int i = 0; i < 8; ++i) O[i] = (f32x4){0.f, 0.f, 0.f, 0.f};
    #pragma unroll
    for (int r = 0; r < 4; ++r) { m_r[r] = sinkv; l_r[r] = 1.0f; }

    const int nkv = qt + 1;   // causal: only tiles up to the diagonal
    for (int t = 0; t < nkv; ++t) {
        const int kv0 = t * KT;
        __syncthreads();

        // ---- stage K tile (coalesced float4 loads, cvt->bf16, swizzled 16B LDS writes)
        #pragma unroll
        for (int p = 0; p < 4; ++p) {
            int idx = tid + p * 256;
            int r = idx >> 4, c = idx & 15;
            const float* src = kg + base + (size_t)(kv0 + r) * HD + c * 8;
            float4 x = *(const float4*)src;
            float4 y = *(const float4*)(src + 4);
            short8 pk;
            pk[0] = (short)f2bf(x.x); pk[1] = (short)f2bf(x.y);
            pk[2] = (short)f2bf(x.z); pk[3] = (short)f2bf(x.w);
            pk[4] = (short)f2bf(y.x); pk[5] = (short)f2bf(y.y);
            pk[6] = (short)f2bf(y.z); pk[7] = (short)f2bf(y.w);
            *(short8*)&Ksh[(r << 7) + ((c ^ (r & 7)) << 3)] = pk;
        }
        // ---- stage V transposed (float4 loads, cvt->bf16, conflict-aware scalar LDS writes)
        {
            int vr = lane;          // kv row
            int c0 = wave;
            #pragma unroll
            for (int p = 0; p < 4; ++p) {
                int c = c0 + (p << 2);
                const float* src = vg + base + (size_t)(kv0 + vr) * HD + c * 8;
                float4 x = *(const float4*)src;
                float4 y = *(const float4*)(src + 4);
                float vals[8] = {x.x, x.y, x.z, x.w, y.x, y.y, y.z, y.w};
                #pragma unroll
                for (int j = 0; j < 8; ++j) {
                    int d = c * 8 + j;  // d&7 == j
                    Vsh[(d << 6) + (((vr >> 3) ^ j) << 3) + (vr & 7)] = f2bf(vals[j]);
                }
            }
        }
        __syncthreads();

        // ---- S = Q K^T  (4 col-blocks of 16, 4 k-steps over D=128)
        f32x4 Sv[4];
        #pragma unroll
        for (int blk = 0; blk < 4; ++blk) {
            f32x4 acc = (f32x4){0.f, 0.f, 0.f, 0.f};
            #pragma unroll
            for (int ks = 0; ks < 4; ++ks) {
                int ch = ((ks << 2) + quad) ^ (l16 & 7);
                short8 kf = *(const short8*)&Ksh[(((blk << 4) + l16) << 7) + (ch << 3)];
                acc = __builtin_amdgcn_mfma_f32_16x16x32_bf16(qf[ks], kf, acc, 0, 0, 0);
            }
            Sv[blk] = acc;
        }

        // ---- scale + causal mask (diagonal tile only; wave-uniform branch)
        float s[4][4];
        const bool domask = (t == nkv - 1);
        #pragma unroll
        for (int blk = 0; blk < 4; ++blk) {
            #pragma unroll
            for (int r = 0; r < 4; ++r) {
                float x = Sv[blk][r] * SCALE;
                if (domask) {
                    int col = kv0 + (blk << 4) + l16;
                    int row = qrow0 + (quad << 2) + r;
                    if (col > row) x = -1.0e38f;
                }
                s[blk][r] = x;
            }
        }

        // ---- online softmax: row max across 16 lanes of each quad-group
        float mx[4];
        #pragma unroll
        for (int r = 0; r < 4; ++r)
            mx[r] = fmaxf(fmaxf(s[0][r], s[1][r]), fmaxf(s[2][r], s[3][r]));
        #pragma unroll
        for (int off = 1; off < 16; off <<= 1)
            #pragma unroll
            for (int r = 0; r < 4; ++r)
                mx[r] = fmaxf(mx[r], __shfl_xor(mx[r], off, 64));

        float mn[4], alpha[4], rs[4];
        #pragma unroll
        for (int r = 0; r < 4; ++r) {
            mn[r] = fmaxf(m_r[r], mx[r]);
            alpha[r] = exp2f((m_r[r] - mn[r]) * LOG2E);
            m_r[r] = mn[r];
            rs[r] = 0.f;
        }

        // ---- P = exp(s - m), write to per-wave LDS (C-layout -> A-layout transform)
        u16* Pw = Psh[wave];
        #pragma unroll
        for (int blk = 0; blk < 4; ++blk) {
            int colhi = (blk << 1) + (l16 >> 3);
            int collo = l16 & 7;
            #pragma unroll
            for (int r = 0; r < 4; ++r) {
                float p = exp2f((s[blk][r] - mn[r]) * LOG2E);
                rs[r] += p;
                int row = (quad << 2) + r;
                Pw[(row << 6) + ((colhi ^ (row & 7)) << 3) + collo] = f2bf(p);
            }
        }
        #pragma unroll
        for (int off = 1; off < 16; off <<= 1)
            #pragma unroll
            for (int r = 0; r < 4; ++r)
                rs[r] += __shfl_xor(rs[r], off, 64);
        #pragma unroll
        for (int r = 0; r < 4; ++r) l_r[r] = l_r[r] * alpha[r] + rs[r];

        // rescale O accumulator
        #pragma unroll
        for (int ob = 0; ob < 8; ++ob)
            #pragma unroll
            for (int r = 0; r < 4; ++r) O[ob][r] *= alpha[r];

        __syncthreads();

        // ---- O += P V   (P: A-operand from LDS; V^T: B-operand from LDS)
        #pragma unroll
        for (int ks2 = 0; ks2 < 2; ++ks2) {
            int ch = ((ks2 << 2) + quad) ^ (l16 & 7);
            short8 pf = *(const short8*)&Pw[(l16 << 6) + (ch << 3)];
            #pragma unroll
            for (int ob = 0; ob < 8; ++ob) {
                int n = (ob << 4) + l16;
                short8 vf = *(const short8*)&Vsh[(n << 6) + (ch << 3)];
                O[ob] = __builtin_amdgcn_mfma_f32_16x16x32_bf16(pf, vf, O[ob], 0, 0, 0);
            }
        }
    }

    // ---- epilogue: normalize by l (which already includes the sink term) and store fp32
    #pragma unroll
    for (int r = 0; r < 4; ++r) l_r[r] = 1.0f / l_r[r];
    #pragma unroll
    for (int ob = 0; ob < 8; ++ob) {
        #pragma unroll
        for (int r = 0; r < 4; ++r) {
            int row = qrow0 + (quad << 2) + r;
            og[base + (size_t)row * HD + (ob << 4) + l16] = O[ob][r] * l_r[r];
        }
    }
}

extern "C" void kernel_launch(void* const* d_in, const int* in_sizes, int n_in,
                              void* d_out, int out_size, void* d_ws, size_t ws_size,
                              hipStream_t stream) {
    const float* q = (const float*)d_in[0];
    const float* k = (const float*)d_in[1];
    const float* v = (const float*)d_in[2];
    const float* s = (const float*)d_in[3];
    float* out = (float*)d_out;
    // grid: (qt | chunk | head | batch) = 16 * 4 * 16 * 4 = 4096 blocks
    dim3 grid(Bq * Hq * (Sq / CHUNK) * (CHUNK / QT));
    attn_sink_kernel<<<grid, 256, 0, stream>>>(q, k, v, s, out);
}